// Round 2
// baseline (146.246 us; speedup 1.0000x reference)
//
#include <hip/hip_runtime.h>

// KroneckerProjection: out = X @ kron(A,B), factored — never materialize C.
//   X: [16384, 2048] fp32, A: [128,16], B: [16,512], out: [16384, 8192] fp32
//   T[r][j][k] = sum_i x[r][i*16+k] * A[i][j]   (per row, 16x16)
//   out[r][j*512+l] = sum_k T[r][j][k] * B[k][l]
//
// LDS-free design: one wave owns 4 rows. lane=(r,k): r=lane>>4, k=lane&15.
//  - Step 1: lane accumulates T[j] (j=0..15) for its (row,k). x read direct
//    from global (lane pattern is linear -> coalesced); A is wave-uniform ->
//    s_load on the scalar pipe.
//  - Step 2: T broadcast via v_readlane (VALU, no LDS); B held entirely in
//    VGPRs (each lane covers out columns l0..l0+3 and l0+256..l0+259).
// Zero LDS, zero barriers. HBM-bound: 128 MiB read + 512 MiB write.

#define DIN   2048
#define DOUT  8192
#define S_DIM 512

__device__ __forceinline__ float rl_f32(float v, int srclane) {
    return __int_as_float(__builtin_amdgcn_readlane(__float_as_int(v), srclane));
}

__global__ __launch_bounds__(256)
void kron_proj_kernel(const float* __restrict__ x,
                      const float* __restrict__ A,
                      const float* __restrict__ B,
                      float* __restrict__ out)
{
    const int t    = threadIdx.x;
    const int lane = t & 63;
    const int wid  = blockIdx.x * 4 + (t >> 6);   // global wave id, 0..4095
    const int r    = lane >> 4;                   // row within wave's group
    const int k    = lane & 15;                   // k-slot this lane owns
    const int row0 = wid * 4;

    // ---- B into registers: lane covers l = [l0, l0+4) and [l0+256, l0+260)
    const int l0 = lane * 4;
    float4 Bl[16], Bh[16];
#pragma unroll
    for (int kk = 0; kk < 16; ++kk) {
        Bl[kk] = *(const float4*)(B + kk * S_DIM + l0);
        Bh[kk] = *(const float4*)(B + kk * S_DIM + 256 + l0);
    }

    // ---- Step 1: T[j] = sum_i x[(row0+r)*2048 + i*16 + k] * A[i*16 + j]
    float T[16];
#pragma unroll
    for (int j = 0; j < 16; ++j) T[j] = 0.f;

    const float* xr = x + (size_t)(row0 + r) * DIN + k;
#pragma unroll 8
    for (int i = 0; i < 128; ++i) {
        const float xv = xr[i * 16];          // 4x64B coalesced per wave instr
        const float* Ar = A + i * 16;         // uniform address -> s_load
#pragma unroll
        for (int j = 0; j < 16; ++j)
            T[j] = fmaf(xv, Ar[j], T[j]);
    }

    // ---- Step 2: out[r2][j*512+l] = sum_k T[r2][j][k] * B[k][l]
    for (int r2 = 0; r2 < 4; ++r2) {
        float* orow = out + (size_t)(row0 + r2) * DOUT;
#pragma unroll
        for (int j = 0; j < 16; ++j) {        // j unrolled: T[j] const-indexed
            float4 aL = make_float4(0.f, 0.f, 0.f, 0.f);
            float4 aH = make_float4(0.f, 0.f, 0.f, 0.f);
#pragma unroll
            for (int kk = 0; kk < 16; ++kk) {
                const float sT = rl_f32(T[j], r2 * 16 + kk);  // T[r2][j][kk]
                aL.x = fmaf(sT, Bl[kk].x, aL.x);
                aL.y = fmaf(sT, Bl[kk].y, aL.y);
                aL.z = fmaf(sT, Bl[kk].z, aL.z);
                aL.w = fmaf(sT, Bl[kk].w, aL.w);
                aH.x = fmaf(sT, Bh[kk].x, aH.x);
                aH.y = fmaf(sT, Bh[kk].y, aH.y);
                aH.z = fmaf(sT, Bh[kk].z, aH.z);
                aH.w = fmaf(sT, Bh[kk].w, aH.w);
            }
            *(float4*)(orow + j * S_DIM + l0) = aL;           // 1KB contiguous
            *(float4*)(orow + j * S_DIM + 256 + l0) = aH;     // 1KB contiguous
        }
    }
}

extern "C" void kernel_launch(void* const* d_in, const int* in_sizes, int n_in,
                              void* d_out, int out_size, void* d_ws, size_t ws_size,
                              hipStream_t stream) {
    const float* x = (const float*)d_in[0];
    const float* A = (const float*)d_in[1];
    const float* B = (const float*)d_in[2];
    float* out = (float*)d_out;

    const int nrows  = in_sizes[0] / DIN;   // 16384
    const int nwaves = nrows / 4;           // 4096 waves, 4 rows each
    const int grid   = nwaves / 4;          // 1024 blocks of 4 waves

    kron_proj_kernel<<<dim3(grid), dim3(256), 0, stream>>>(x, A, B, out);
}

// Round 3
// 142.126 us; speedup vs baseline: 1.0290x; 1.0290x over previous
//
#include <hip/hip_runtime.h>

// KroneckerProjection: out = X @ kron(A,B), factored — never materialize C.
//   X: [16384, 2048] fp32, A: [128,16], B: [16,512], out: [16384, 8192] fp32
//   T[r][j][k] = sum_i x[r][i*16+k] * A[i][j]   (per row, 16x16)
//   out[r][j*512+l] = sum_k T[r][j][k] * B[k][l]
//
// LDS-free, occupancy-first design: one wave owns 4 rows. lane=(r,k).
//  - Step 1: lane accumulates T[j] (j=0..15) for its (row,k). x direct from
//    global (coalesced); A wave-uniform -> scalar loads.
//  - Step 2: TWO passes over column halves (256 cols each). Per pass, B half
//    lives in 64 VGPRs (16 x float4/lane); T broadcast via v_readlane.
//    '#pragma unroll 1' on the pass loop keeps only one B half live ->
//    VGPR <= 128 -> 4 waves/SIMD (vs 2 before) to overlap VALU with HBM.
// Zero LDS, zero barriers. HBM floor: 128 MiB read + 512 MiB write ~ 101 us.

#define DIN   2048
#define DOUT  8192
#define S_DIM 512

__device__ __forceinline__ float rl_f32(float v, int srclane) {
    return __int_as_float(__builtin_amdgcn_readlane(__float_as_int(v), srclane));
}

__global__ __launch_bounds__(256, 4)
void kron_proj_kernel(const float* __restrict__ x,
                      const float* __restrict__ A,
                      const float* __restrict__ B,
                      float* __restrict__ out)
{
    const int t    = threadIdx.x;
    const int lane = t & 63;
    const int wid  = blockIdx.x * 4 + (t >> 6);   // global wave id, 0..4095
    const int r    = lane >> 4;                   // row within wave's group
    const int k    = lane & 15;                   // k-slot this lane owns
    const int row0 = wid * 4;

    // ---- Step 1: T[j] = sum_i x[(row0+r)*2048 + i*16 + k] * A[i*16 + j]
    float T[16];
#pragma unroll
    for (int j = 0; j < 16; ++j) T[j] = 0.f;

    const float* xr = x + (size_t)(row0 + r) * DIN + k;
#pragma unroll 8
    for (int i = 0; i < 128; ++i) {
        const float xv = xr[i * 16];          // 4x64B coalesced per wave instr
        const float* Ar = A + i * 16;         // uniform address -> s_load
#pragma unroll
        for (int j = 0; j < 16; ++j)
            T[j] = fmaf(xv, Ar[j], T[j]);
    }

    // ---- Step 2: two passes over column halves; one B half in regs at a time
#pragma unroll 1
    for (int p = 0; p < 2; ++p) {
        const int c0 = p * 256 + lane * 4;    // this lane's 4 columns
        float4 Breg[16];
#pragma unroll
        for (int kk = 0; kk < 16; ++kk)
            Breg[kk] = *(const float4*)(B + kk * S_DIM + c0);

#pragma unroll
        for (int r2 = 0; r2 < 4; ++r2) {
            float* orow = out + (size_t)(row0 + r2) * DOUT + c0;
#pragma unroll
            for (int j = 0; j < 16; ++j) {    // j unrolled: T[j] const-indexed
                float4 acc = make_float4(0.f, 0.f, 0.f, 0.f);
#pragma unroll
                for (int kk = 0; kk < 16; ++kk) {
                    const float sT = rl_f32(T[j], r2 * 16 + kk);  // T[r2][j][kk]
                    acc.x = fmaf(sT, Breg[kk].x, acc.x);
                    acc.y = fmaf(sT, Breg[kk].y, acc.y);
                    acc.z = fmaf(sT, Breg[kk].z, acc.z);
                    acc.w = fmaf(sT, Breg[kk].w, acc.w);
                }
                *(float4*)(orow + j * S_DIM) = acc;   // 1KB contiguous / wave
            }
        }
    }
}

extern "C" void kernel_launch(void* const* d_in, const int* in_sizes, int n_in,
                              void* d_out, int out_size, void* d_ws, size_t ws_size,
                              hipStream_t stream) {
    const float* x = (const float*)d_in[0];
    const float* A = (const float*)d_in[1];
    const float* B = (const float*)d_in[2];
    float* out = (float*)d_out;

    const int nrows  = in_sizes[0] / DIN;   // 16384
    const int nwaves = nrows / 4;           // 4096 waves, 4 rows each
    const int grid   = nwaves / 4;          // 1024 blocks of 4 waves

    kron_proj_kernel<<<dim3(grid), dim3(256), 0, stream>>>(x, A, B, out);
}